// Round 4
// baseline (2795.306 us; speedup 1.0000x reference)
//
#include <hip/hip_runtime.h>
#include <hip/hip_bf16.h>
#include <cstdint>
#include <cstddef>
#include <type_traits>

#define B_ALL 256
#define T_LEN 512
#define D_INP 64
#define HD    128
#define G4    512            // 4*H
#define NC    12
#define BCH   128            // batch per chunk
#define ROWS  (BCH * T_LEN)  // 65536 rows per chunk

// ---------- helpers ----------
__device__ __forceinline__ float bf2f(unsigned short u) {
    union { unsigned int i; float f; } v; v.i = ((unsigned int)u) << 16; return v.f;
}
__device__ __forceinline__ unsigned short f2bf(float f) {
    union { float f; unsigned int i; } v; v.f = f;
    unsigned int r = v.i + 0x7FFFu + ((v.i >> 16) & 1u);  // round-nearest-even
    return (unsigned short)(r >> 16);
}
__device__ __forceinline__ float sigf(float x) { return 1.0f / (1.0f + __expf(-x)); }
__device__ __forceinline__ float tanh_f(float x) {
    float xx = fminf(15.0f, fmaxf(-15.0f, x));
    float e = __expf(2.0f * xx);
    return (e - 1.0f) / (e + 1.0f);
}

// LDS-only barrier: drains lgkmcnt (ds/shfl ops) but leaves global loads/stores
// in flight (no vmcnt(0) drain, unlike __syncthreads).
#define LDS_BARRIER() asm volatile("s_waitcnt lgkmcnt(0)\n\ts_barrier" ::: "memory")

using bf16x8 = __attribute__((ext_vector_type(8))) short;
using f32x4  = __attribute__((ext_vector_type(4))) float;

// XOR swizzle for [R][32] bf16 LDS tiles (64B rows). Toggles byte bits 4-5
// within each row -> frag-read lanes (stride 64B) spread over 4 bank groups.
__device__ __forceinline__ int swz(int r, int kb) {
    return (r * 64 + kb) ^ ((r & 3) << 4);
}

// ---------- W split: fp32 -> hi/lo bf16 pair (hi+lo ~ fp32 exact) ----------
__global__ __launch_bounds__(256)
void split_w(const float* __restrict__ w, unsigned short* __restrict__ hi,
             unsigned short* __restrict__ lo, int n)
{
    int i = blockIdx.x * 256 + threadIdx.x;
    if (i < n) {
        float f = w[i];
        unsigned short h = f2bf(f);
        hi[i] = h;
        lo[i] = f2bf(f - bf2f(h));
    }
}

// ---------- gates GEMM (MFMA, split-precision bf16) — unchanged from R3 ----------
template <int TERMS, typename TA>
__global__ __launch_bounds__(256)
void gates_gemm_mfma(const TA* __restrict__ A,
                     const unsigned short* __restrict__ Whi_g,
                     const unsigned short* __restrict__ Wlo_g,
                     const float* __restrict__ bias,
                     const int* __restrict__ lens,
                     unsigned short* __restrict__ out, int K)
{
    int row0 = blockIdx.x * 128;
    int col0 = blockIdx.y * 128;
    int bl = row0 >> 9;
    int t0 = row0 & (T_LEN - 1);
    if (t0 >= lens[bl]) return;

    __shared__ __align__(16) char smem[TERMS == 3 ? 32768 : 24576];
    char* sAhi = smem;                 // [128][32] bf16, swizzled
    char* sWhi = smem + 8192;
    char* sWlo = smem + 16384;
    char* sAlo = (TERMS == 3) ? smem + 24576 : smem;  // unused if TERMS==2

    int tid = threadIdx.x;
    int l   = tid & 63;
    int w   = tid >> 6;
    int wr  = (w >> 1) * 64;           // wave row offset in tile
    int wc  = (w & 1) * 64;            // wave col offset in tile

    f32x4 acc[4][4];
#pragma unroll
    for (int mi = 0; mi < 4; ++mi)
#pragma unroll
        for (int ni = 0; ni < 4; ++ni) acc[mi][ni] = (f32x4){0.f, 0.f, 0.f, 0.f};

    int fr = l & 15;                   // frag row/col within 16
    int fk = (l >> 4) * 16;            // frag k-byte offset (8 bf16)

    for (int kt = 0; kt < K; kt += 32) {
#pragma unroll
        for (int q = 0; q < 2; ++q) {
            int c = tid + 256 * q;
            int r = c >> 2, kc = c & 3;
            size_t gi = (size_t)(col0 + r) * K + kt + kc * 8;
            *(uint4*)(sWhi + swz(r, kc * 16)) = *(const uint4*)&Whi_g[gi];
            *(uint4*)(sWlo + swz(r, kc * 16)) = *(const uint4*)&Wlo_g[gi];
        }
        if constexpr (std::is_same<TA, unsigned short>::value) {
#pragma unroll
            for (int q = 0; q < 2; ++q) {
                int c = tid + 256 * q;
                int r = c >> 2, kc = c & 3;
                *(uint4*)(sAhi + swz(r, kc * 16)) =
                    *(const uint4*)&A[(size_t)(row0 + r) * K + kt + kc * 8];
            }
        } else {
#pragma unroll
            for (int q = 0; q < 4; ++q) {
                int c = tid + 256 * q;
                int r = c >> 3, kc = c & 7;
                float4 f = *(const float4*)&A[(size_t)(row0 + r) * K + kt + kc * 4];
                ushort4 h, lo;
                h.x = f2bf(f.x); lo.x = f2bf(f.x - bf2f(h.x));
                h.y = f2bf(f.y); lo.y = f2bf(f.y - bf2f(h.y));
                h.z = f2bf(f.z); lo.z = f2bf(f.z - bf2f(h.z));
                h.w = f2bf(f.w); lo.w = f2bf(f.w - bf2f(h.w));
                *(ushort4*)(sAhi + swz(r, kc * 8)) = h;
                *(ushort4*)(sAlo + swz(r, kc * 8)) = lo;
            }
        }
        __syncthreads();

        bf16x8 ah[4], al[4], bh[4], bl4[4];
#pragma unroll
        for (int mi = 0; mi < 4; ++mi) {
            int off = swz(wr + mi * 16 + fr, fk);
            ah[mi] = *(const bf16x8*)(sAhi + off);
            if (TERMS == 3) al[mi] = *(const bf16x8*)(sAlo + off);
        }
#pragma unroll
        for (int ni = 0; ni < 4; ++ni) {
            int off = swz(wc + ni * 16 + fr, fk);
            bh[ni]  = *(const bf16x8*)(sWhi + off);
            bl4[ni] = *(const bf16x8*)(sWlo + off);
        }
#pragma unroll
        for (int mi = 0; mi < 4; ++mi)
#pragma unroll
            for (int ni = 0; ni < 4; ++ni) {
                acc[mi][ni] = __builtin_amdgcn_mfma_f32_16x16x32_bf16(
                    ah[mi], bh[ni], acc[mi][ni], 0, 0, 0);
                acc[mi][ni] = __builtin_amdgcn_mfma_f32_16x16x32_bf16(
                    ah[mi], bl4[ni], acc[mi][ni], 0, 0, 0);
                if (TERMS == 3)
                    acc[mi][ni] = __builtin_amdgcn_mfma_f32_16x16x32_bf16(
                        al[mi], bh[ni], acc[mi][ni], 0, 0, 0);
            }
        __syncthreads();
    }

    int r4 = (l >> 4) * 4;
#pragma unroll
    for (int ni = 0; ni < 4; ++ni) {
        int col = col0 + wc + ni * 16 + fr;
        float bj = bias[col];
#pragma unroll
        for (int mi = 0; mi < 4; ++mi) {
            int row = row0 + wr + mi * 16 + r4;
            f32x4 v = acc[mi][ni];
#pragma unroll
            for (int r = 0; r < 4; ++r)
                out[(size_t)(row + r) * 1024 + col] = f2bf(v[r] + bj);
        }
    }
}

// ---------- LSTM recurrence (R4 rewrite) ----------
// tid = rr*4 + ks: rr = hdim 0..127, ks = k-slice 0..3. Thread computes the
// 4 gate partials (i,f,g,o of hdim rr) over k in [32ks, 32ks+32).
// The 4 k-partials live in 4 ADJACENT LANES of one wave -> __shfl_xor(1),(2)
// butterfly gives every lane all 4 full gate sums: no gp LDS, no barrier
// between dot and nonlinearity. All 4 lanes run the nonlinearity redundantly
// (trans cost is per wave-inst, not per lane -> spreads exp/div over 8 waves
// instead of 2). h ping-pongs between two LDS buffers -> the WAR hazard is
// gone and there is ONE lgkm-only barrier per step (was 2 full barriers).
// h slices padded to stride 36 f32 (16B aligned, conflict-free 4-way reads).
__global__ __launch_bounds__(512)
void lstm_rec(const unsigned short* __restrict__ xg,   // [ROWS][1024]
              const float* __restrict__ Whh,           // [2][512][128]
              const int* __restrict__ lens,            // chunk-offset
              unsigned short* __restrict__ hs,         // [ROWS][256] or null
              float* __restrict__ hTf, float* __restrict__ hTb,
              int bOff)
{
    int dir = blockIdx.x >> 7;
    int bl  = blockIdx.x & 127;
    int L   = lens[bl];
    int tid = threadIdx.x;
    int rr  = tid >> 2;          // hdim 0..127
    int ks  = tid & 3;           // k-slice 0..3

    // ping-pong h buffers; slice ks at [ks*36, ks*36+32) (pad 4 -> no bank conflict)
    __shared__ float h_s[2][144];

    // w[g][kk] = Whh[dir][g*128 + rr][ks*32 + kk]
    float w[4][32];
#pragma unroll
    for (int g = 0; g < 4; ++g) {
        const float* wrow = Whh + ((size_t)dir * G4 + g * HD + rr) * HD + ks * 32;
#pragma unroll
        for (int k = 0; k < 32; k += 4) {
            float4 v = *(const float4*)(wrow + k);
            w[g][k] = v.x; w[g][k + 1] = v.y; w[g][k + 2] = v.z; w[g][k + 3] = v.w;
        }
    }

    if (tid < 144) { h_s[0][tid] = 0.0f; h_s[1][tid] = 0.0f; }
    float c = 0.0f, hkeep = 0.0f;
    __syncthreads();

    const unsigned short* xgb = xg + (size_t)bl * T_LEN * 1024 + (size_t)dir * G4;
    int tt   = dir ? (L - 1) : 0;
    int step = dir ? -1 : 1;

    // preload step-0 gate biases (4 lanes of a group load same addrs -> broadcast)
    float xv0, xv1, xv2, xv3;
    {
        const unsigned short* p = xgb + (size_t)tt * 1024;
        xv0 = bf2f(p[rr]);       xv1 = bf2f(p[rr + 128]);
        xv2 = bf2f(p[rr + 256]); xv3 = bf2f(p[rr + 384]);
    }

    int cur = 0;
    for (int t = 0; t < L; ++t) {
        // ---- dot: 4 independent 32-deep chains ----
        float a0 = 0.f, a1 = 0.f, a2 = 0.f, a3 = 0.f;
        const float* hq = &h_s[cur][ks * 36];
#pragma unroll
        for (int k = 0; k < 32; k += 4) {
            float4 h4 = *(const float4*)(hq + k);
            a0 += w[0][k] * h4.x + w[0][k+1] * h4.y + w[0][k+2] * h4.z + w[0][k+3] * h4.w;
            a1 += w[1][k] * h4.x + w[1][k+1] * h4.y + w[1][k+2] * h4.z + w[1][k+3] * h4.w;
            a2 += w[2][k] * h4.x + w[2][k+1] * h4.y + w[2][k+2] * h4.z + w[2][k+3] * h4.w;
            a3 += w[3][k] * h4.x + w[3][k+1] * h4.y + w[3][k+2] * h4.z + w[3][k+3] * h4.w;
        }
        // ---- in-wave butterfly over the 4-lane k-group ----
        a0 += __shfl_xor(a0, 1); a1 += __shfl_xor(a1, 1);
        a2 += __shfl_xor(a2, 1); a3 += __shfl_xor(a3, 1);
        a0 += __shfl_xor(a0, 2); a1 += __shfl_xor(a1, 2);
        a2 += __shfl_xor(a2, 2); a3 += __shfl_xor(a3, 2);

        float gi = a0 + xv0, gf = a1 + xv1, gg = a2 + xv2, go = a3 + xv3;

        // prefetch next step's biases (in flight across barrier; used next iter)
        int ttn = (t + 1 < L) ? (tt + step) : tt;
        {
            const unsigned short* p = xgb + (size_t)ttn * 1024;
            xv0 = bf2f(p[rr]);       xv1 = bf2f(p[rr + 128]);
            xv2 = bf2f(p[rr + 256]); xv3 = bf2f(p[rr + 384]);
        }

        // ---- nonlinearity: redundant across the 4 lanes (free in wave-cycles) ----
        float I = sigf(gi);
        float F = sigf(gf);
        float G = tanh_f(gg);
        float O = sigf(go);
        c = F * c + I * G;
        float hn = O * tanh_f(c);
        hkeep = hn;

        int nxt = cur ^ 1;
        if (ks == 0) {
            h_s[nxt][(rr >> 5) * 36 + (rr & 31)] = hn;
            if (hs) hs[(size_t)(bl * T_LEN + tt) * 256 + dir * HD + rr] = f2bf(hn);
        }
        LDS_BARRIER();
        cur = nxt;
        tt += step;
    }
    if (hTf && ks == 0) {
        (dir ? hTb : hTf)[(size_t)(bOff + bl) * HD + rr] = hkeep;
    }
}

// ---------- final FC + log_softmax ----------
__global__ __launch_bounds__(256)
void fc_lsm(const float* __restrict__ hTf, const float* __restrict__ hTb,
            const float* __restrict__ Wfc, const float* __restrict__ bfc,
            float* __restrict__ out)
{
    int b = threadIdx.x;
    const float* hb = hTb + (size_t)b * HD;
    const float* hf = hTf + (size_t)b * HD;
    float l[NC];
#pragma unroll
    for (int cc = 0; cc < NC; ++cc) {
        const float* wr = Wfc + cc * 256;
        float acc = bfc[cc];
        for (int k = 0; k < HD; k += 4) {
            acc += hb[k] * wr[k] + hb[k + 1] * wr[k + 1]
                 + hb[k + 2] * wr[k + 2] + hb[k + 3] * wr[k + 3];
            acc += hf[k] * wr[128 + k] + hf[k + 1] * wr[128 + k + 1]
                 + hf[k + 2] * wr[128 + k + 2] + hf[k + 3] * wr[128 + k + 3];
        }
        l[cc] = acc;
    }
    float m = l[0];
#pragma unroll
    for (int cc = 1; cc < NC; ++cc) m = fmaxf(m, l[cc]);
    float s = 0.0f;
#pragma unroll
    for (int cc = 0; cc < NC; ++cc) s += __expf(l[cc] - m);
    float lg = m + logf(s);
#pragma unroll
    for (int cc = 0; cc < NC; ++cc) out[(size_t)b * NC + cc] = l[cc] - lg;
}

extern "C" void kernel_launch(void* const* d_in, const int* in_sizes, int n_in,
                              void* d_out, int out_size, void* d_ws, size_t ws_size,
                              hipStream_t stream)
{
    const float* X    = (const float*)d_in[0];
    const int*   len  = (const int*)d_in[1];
    const float* Wih0 = (const float*)d_in[2];   // (2,512,64)  -> (1024,64)
    const float* Whh0 = (const float*)d_in[3];   // (2,512,128)
    const float* b0   = (const float*)d_in[4];   // (2,512) -> (1024)
    const float* Wih1 = (const float*)d_in[5];   // (2,512,256) -> (1024,256)
    const float* Whh1 = (const float*)d_in[6];
    const float* b1   = (const float*)d_in[7];
    const float* Wfc  = (const float*)d_in[8];   // (12,256)
    const float* bfc  = (const float*)d_in[9];   // (12)
    float* out = (float*)d_out;

    char* ws = (char*)d_ws;
    size_t off = 0;
    unsigned short* xg = (unsigned short*)(ws + off); off += (size_t)ROWS * 1024 * 2;
    unsigned short* h1 = (unsigned short*)(ws + off); off += (size_t)ROWS * 256 * 2;
    float* hTf = (float*)(ws + off); off += (size_t)B_ALL * HD * 4;
    float* hTb = (float*)(ws + off); off += (size_t)B_ALL * HD * 4;
    unsigned short* W0hi = (unsigned short*)(ws + off); off += 1024 * 64 * 2;
    unsigned short* W0lo = (unsigned short*)(ws + off); off += 1024 * 64 * 2;
    unsigned short* W1hi = (unsigned short*)(ws + off); off += 1024 * 256 * 2;
    unsigned short* W1lo = (unsigned short*)(ws + off); off += 1024 * 256 * 2;

    split_w<<<(1024 * 64 + 255) / 256, 256, 0, stream>>>(Wih0, W0hi, W0lo, 1024 * 64);
    split_w<<<(1024 * 256 + 255) / 256, 256, 0, stream>>>(Wih1, W1hi, W1lo, 1024 * 256);

    for (int ch = 0; ch < 2; ++ch) {
        const int* lc = len + ch * BCH;
        const float* Xc = X + (size_t)ch * BCH * T_LEN * D_INP;

        gates_gemm_mfma<3, float><<<dim3(ROWS / 128, 8), 256, 0, stream>>>(
            Xc, W0hi, W0lo, b0, lc, xg, D_INP);
        lstm_rec<<<2 * BCH, 512, 0, stream>>>(xg, Whh0, lc, h1, nullptr, nullptr, 0);
        gates_gemm_mfma<2, unsigned short><<<dim3(ROWS / 128, 8), 256, 0, stream>>>(
            h1, W1hi, W1lo, b1, lc, xg, 2 * HD);
        lstm_rec<<<2 * BCH, 512, 0, stream>>>(xg, Whh1, lc, nullptr, hTf, hTb, ch * BCH);
    }
    fc_lsm<<<1, 256, 0, stream>>>(hTf, hTb, Wfc, bfc, out);
}

// Round 5
// 2365.705 us; speedup vs baseline: 1.1816x; 1.1816x over previous
//
#include <hip/hip_runtime.h>
#include <hip/hip_bf16.h>
#include <cstdint>
#include <cstddef>
#include <type_traits>

#define B_ALL 256
#define T_LEN 512
#define D_INP 64
#define HD    128
#define G4    512            // 4*H
#define NC    12
#define BCH   128            // batch per chunk (fallback path)
#define ROWS  (BCH * T_LEN)  // 65536 rows per chunk
#define ROWS_ALL (B_ALL * T_LEN)

// ---------- helpers ----------
__device__ __forceinline__ float bf2f(unsigned short u) {
    union { unsigned int i; float f; } v; v.i = ((unsigned int)u) << 16; return v.f;
}
__device__ __forceinline__ unsigned short f2bf(float f) {
    union { float f; unsigned int i; } v; v.f = f;
    unsigned int r = v.i + 0x7FFFu + ((v.i >> 16) & 1u);  // round-nearest-even
    return (unsigned short)(r >> 16);
}
__device__ __forceinline__ float sigf(float x) { return 1.0f / (1.0f + __expf(-x)); }
__device__ __forceinline__ float tanh_f(float x) {
    float xx = fminf(15.0f, fmaxf(-15.0f, x));
    float e = __expf(2.0f * xx);
    return (e - 1.0f) / (e + 1.0f);
}

// LDS-only barrier: drains lgkmcnt but leaves global loads/stores in flight.
#define LDS_BARRIER() asm volatile("s_waitcnt lgkmcnt(0)\n\ts_barrier" ::: "memory")

using bf16x8 = __attribute__((ext_vector_type(8))) short;
using f32x4  = __attribute__((ext_vector_type(4))) float;

// XOR swizzle for [R][32] bf16 LDS tiles (64B rows).
__device__ __forceinline__ int swz(int r, int kb) {
    return (r * 64 + kb) ^ ((r & 3) << 4);
}

// ---------- W split: fp32 -> hi/lo bf16 pair (hi+lo ~ fp32 exact) ----------
__global__ __launch_bounds__(256)
void split_w(const float* __restrict__ w, unsigned short* __restrict__ hi,
             unsigned short* __restrict__ lo, int n)
{
    int i = blockIdx.x * 256 + threadIdx.x;
    if (i < n) {
        float f = w[i];
        unsigned short h = f2bf(f);
        hi[i] = h;
        lo[i] = f2bf(f - bf2f(h));
    }
}

// ---------- gates GEMM (MFMA, split-precision bf16) — unchanged from R3 ----------
template <int TERMS, typename TA>
__global__ __launch_bounds__(256)
void gates_gemm_mfma(const TA* __restrict__ A,
                     const unsigned short* __restrict__ Whi_g,
                     const unsigned short* __restrict__ Wlo_g,
                     const float* __restrict__ bias,
                     const int* __restrict__ lens,
                     unsigned short* __restrict__ out, int K)
{
    int row0 = blockIdx.x * 128;
    int col0 = blockIdx.y * 128;
    int bl = row0 >> 9;
    int t0 = row0 & (T_LEN - 1);
    if (t0 >= lens[bl]) return;

    __shared__ __align__(16) char smem[TERMS == 3 ? 32768 : 24576];
    char* sAhi = smem;                 // [128][32] bf16, swizzled
    char* sWhi = smem + 8192;
    char* sWlo = smem + 16384;
    char* sAlo = (TERMS == 3) ? smem + 24576 : smem;

    int tid = threadIdx.x;
    int l   = tid & 63;
    int w   = tid >> 6;
    int wr  = (w >> 1) * 64;
    int wc  = (w & 1) * 64;

    f32x4 acc[4][4];
#pragma unroll
    for (int mi = 0; mi < 4; ++mi)
#pragma unroll
        for (int ni = 0; ni < 4; ++ni) acc[mi][ni] = (f32x4){0.f, 0.f, 0.f, 0.f};

    int fr = l & 15;
    int fk = (l >> 4) * 16;

    for (int kt = 0; kt < K; kt += 32) {
#pragma unroll
        for (int q = 0; q < 2; ++q) {
            int c = tid + 256 * q;
            int r = c >> 2, kc = c & 3;
            size_t gi = (size_t)(col0 + r) * K + kt + kc * 8;
            *(uint4*)(sWhi + swz(r, kc * 16)) = *(const uint4*)&Whi_g[gi];
            *(uint4*)(sWlo + swz(r, kc * 16)) = *(const uint4*)&Wlo_g[gi];
        }
        if constexpr (std::is_same<TA, unsigned short>::value) {
#pragma unroll
            for (int q = 0; q < 2; ++q) {
                int c = tid + 256 * q;
                int r = c >> 2, kc = c & 3;
                *(uint4*)(sAhi + swz(r, kc * 16)) =
                    *(const uint4*)&A[(size_t)(row0 + r) * K + kt + kc * 8];
            }
        } else {
#pragma unroll
            for (int q = 0; q < 4; ++q) {
                int c = tid + 256 * q;
                int r = c >> 3, kc = c & 7;
                float4 f = *(const float4*)&A[(size_t)(row0 + r) * K + kt + kc * 4];
                ushort4 h, lo;
                h.x = f2bf(f.x); lo.x = f2bf(f.x - bf2f(h.x));
                h.y = f2bf(f.y); lo.y = f2bf(f.y - bf2f(h.y));
                h.z = f2bf(f.z); lo.z = f2bf(f.z - bf2f(h.z));
                h.w = f2bf(f.w); lo.w = f2bf(f.w - bf2f(h.w));
                *(ushort4*)(sAhi + swz(r, kc * 8)) = h;
                *(ushort4*)(sAlo + swz(r, kc * 8)) = lo;
            }
        }
        __syncthreads();

        bf16x8 ah[4], al[4], bh[4], bl4[4];
#pragma unroll
        for (int mi = 0; mi < 4; ++mi) {
            int off = swz(wr + mi * 16 + fr, fk);
            ah[mi] = *(const bf16x8*)(sAhi + off);
            if (TERMS == 3) al[mi] = *(const bf16x8*)(sAlo + off);
        }
#pragma unroll
        for (int ni = 0; ni < 4; ++ni) {
            int off = swz(wc + ni * 16 + fr, fk);
            bh[ni]  = *(const bf16x8*)(sWhi + off);
            bl4[ni] = *(const bf16x8*)(sWlo + off);
        }
#pragma unroll
        for (int mi = 0; mi < 4; ++mi)
#pragma unroll
            for (int ni = 0; ni < 4; ++ni) {
                acc[mi][ni] = __builtin_amdgcn_mfma_f32_16x16x32_bf16(
                    ah[mi], bh[ni], acc[mi][ni], 0, 0, 0);
                acc[mi][ni] = __builtin_amdgcn_mfma_f32_16x16x32_bf16(
                    ah[mi], bl4[ni], acc[mi][ni], 0, 0, 0);
                if (TERMS == 3)
                    acc[mi][ni] = __builtin_amdgcn_mfma_f32_16x16x32_bf16(
                        al[mi], bh[ni], acc[mi][ni], 0, 0, 0);
            }
        __syncthreads();
    }

    int r4 = (l >> 4) * 4;
#pragma unroll
    for (int ni = 0; ni < 4; ++ni) {
        int col = col0 + wc + ni * 16 + fr;
        float bj = bias[col];
#pragma unroll
        for (int mi = 0; mi < 4; ++mi) {
            int row = row0 + wr + mi * 16 + r4;
            f32x4 v = acc[mi][ni];
#pragma unroll
            for (int r = 0; r < 4; ++r)
                out[(size_t)(row + r) * 1024 + col] = f2bf(v[r] + bj);
        }
    }
}

// ---------- LSTM recurrence: R2 structure (proven fastest), decode-parameterized ----------
// blockIdx.x = dir * nb + bl, nb = 1<<dshift blocks per dir.
// tid = ks*128 + rr: thread computes partials of output rr's 4 gate rows over
// k-quarter ks. Reduce via gp[4][512] LDS; waves 0-1 do the nonlinearity.
__global__ __launch_bounds__(512)
void lstm_rec(const unsigned short* __restrict__ xg,   // [nb*T_LEN][1024]
              const float* __restrict__ Whh,           // [2][512][128]
              const int* __restrict__ lens,
              unsigned short* __restrict__ hs,         // [nb*T_LEN][256] or null
              float* __restrict__ hTf, float* __restrict__ hTb,
              int bOff, int dshift)
{
    int dir = blockIdx.x >> dshift;
    int bl  = blockIdx.x & ((1 << dshift) - 1);
    int L   = lens[bl];
    int tid = threadIdx.x;
    int ks  = tid >> 7;
    int rr  = tid & 127;

    __shared__ float h_s[HD];
    __shared__ float gp[4][G4];

    float w[4][32];
#pragma unroll
    for (int g = 0; g < 4; ++g) {
        const float* wrow = Whh + ((size_t)dir * G4 + g * HD + rr) * HD + ks * 32;
#pragma unroll
        for (int k = 0; k < 32; k += 4) {
            float4 v = *(const float4*)(wrow + k);
            w[g][k] = v.x; w[g][k + 1] = v.y; w[g][k + 2] = v.z; w[g][k + 3] = v.w;
        }
    }

    if (tid < HD) h_s[tid] = 0.0f;
    float c = 0.0f, hkeep = 0.0f;
    __syncthreads();

    const unsigned short* xgb = xg + (size_t)bl * T_LEN * 1024 + (size_t)dir * G4;
    int tt   = dir ? (L - 1) : 0;
    int step = dir ? -1 : 1;

    float xv0 = 0.f, xv1 = 0.f, xv2 = 0.f, xv3 = 0.f;
    if (tid < HD) {
        const unsigned short* p = xgb + (size_t)tt * 1024;
        xv0 = bf2f(p[tid]);       xv1 = bf2f(p[tid + 128]);
        xv2 = bf2f(p[tid + 256]); xv3 = bf2f(p[tid + 384]);
    }

    for (int t = 0; t < L; ++t) {
        float a0 = 0.f, a1 = 0.f, a2 = 0.f, a3 = 0.f;
        const float* hq = &h_s[ks * 32];
#pragma unroll
        for (int k = 0; k < 32; k += 4) {
            float4 h4 = *(const float4*)(hq + k);
            a0 += w[0][k] * h4.x + w[0][k+1] * h4.y + w[0][k+2] * h4.z + w[0][k+3] * h4.w;
            a1 += w[1][k] * h4.x + w[1][k+1] * h4.y + w[1][k+2] * h4.z + w[1][k+3] * h4.w;
            a2 += w[2][k] * h4.x + w[2][k+1] * h4.y + w[2][k+2] * h4.z + w[2][k+3] * h4.w;
            a3 += w[3][k] * h4.x + w[3][k+1] * h4.y + w[3][k+2] * h4.z + w[3][k+3] * h4.w;
        }
        gp[ks][rr]       = a0;
        gp[ks][rr + 128] = a1;
        gp[ks][rr + 256] = a2;
        gp[ks][rr + 384] = a3;
        LDS_BARRIER();

        if (tid < HD) {
            float gi = xv0 + ((gp[0][tid]       + gp[1][tid])       + (gp[2][tid]       + gp[3][tid]));
            float gf = xv1 + ((gp[0][tid + 128] + gp[1][tid + 128]) + (gp[2][tid + 128] + gp[3][tid + 128]));
            float gg = xv2 + ((gp[0][tid + 256] + gp[1][tid + 256]) + (gp[2][tid + 256] + gp[3][tid + 256]));
            float go = xv3 + ((gp[0][tid + 384] + gp[1][tid + 384]) + (gp[2][tid + 384] + gp[3][tid + 384]));

            int ttn = (t + 1 < L) ? (tt + step) : tt;
            const unsigned short* p = xgb + (size_t)ttn * 1024;
            xv0 = bf2f(p[tid]);       xv1 = bf2f(p[tid + 128]);
            xv2 = bf2f(p[tid + 256]); xv3 = bf2f(p[tid + 384]);

            float ig = sigf(gi);
            float fg = sigf(gf);
            float G  = tanh_f(gg);
            float og = sigf(go);
            c = fg * c + ig * G;
            float hn = og * tanh_f(c);
            h_s[tid] = hn;
            hkeep = hn;
            if (hs) hs[(size_t)(bl * T_LEN + tt) * 256 + dir * HD + tid] = f2bf(hn);
        }
        LDS_BARRIER();
        tt += step;
    }
    if (hTf && tid < HD) {
        (dir ? hTb : hTf)[(size_t)(bOff + bl) * HD + tid] = hkeep;
    }
}

// ---------- final FC + log_softmax ----------
__global__ __launch_bounds__(256)
void fc_lsm(const float* __restrict__ hTf, const float* __restrict__ hTb,
            const float* __restrict__ Wfc, const float* __restrict__ bfc,
            float* __restrict__ out)
{
    int b = threadIdx.x;
    const float* hb = hTb + (size_t)b * HD;
    const float* hf = hTf + (size_t)b * HD;
    float l[NC];
#pragma unroll
    for (int cc = 0; cc < NC; ++cc) {
        const float* wr = Wfc + cc * 256;
        float acc = bfc[cc];
        for (int k = 0; k < HD; k += 4) {
            acc += hb[k] * wr[k] + hb[k + 1] * wr[k + 1]
                 + hb[k + 2] * wr[k + 2] + hb[k + 3] * wr[k + 3];
            acc += hf[k] * wr[128 + k] + hf[k + 1] * wr[128 + k + 1]
                 + hf[k + 2] * wr[128 + k + 2] + hf[k + 3] * wr[128 + k + 3];
        }
        l[cc] = acc;
    }
    float m = l[0];
#pragma unroll
    for (int cc = 1; cc < NC; ++cc) m = fmaxf(m, l[cc]);
    float s = 0.0f;
#pragma unroll
    for (int cc = 0; cc < NC; ++cc) s += __expf(l[cc] - m);
    float lg = m + logf(s);
#pragma unroll
    for (int cc = 0; cc < NC; ++cc) out[(size_t)b * NC + cc] = l[cc] - lg;
}

extern "C" void kernel_launch(void* const* d_in, const int* in_sizes, int n_in,
                              void* d_out, int out_size, void* d_ws, size_t ws_size,
                              hipStream_t stream)
{
    const float* X    = (const float*)d_in[0];
    const int*   len  = (const int*)d_in[1];
    const float* Wih0 = (const float*)d_in[2];   // (2,512,64)  -> (1024,64)
    const float* Whh0 = (const float*)d_in[3];   // (2,512,128)
    const float* b0   = (const float*)d_in[4];   // (2,512) -> (1024)
    const float* Wih1 = (const float*)d_in[5];   // (2,512,256) -> (1024,256)
    const float* Whh1 = (const float*)d_in[6];
    const float* b1   = (const float*)d_in[7];
    const float* Wfc  = (const float*)d_in[8];   // (12,256)
    const float* bfc  = (const float*)d_in[9];   // (12)
    float* out = (float*)d_out;

    const size_t wsplit_bytes = (size_t)(1024 * 64 * 2 + 1024 * 256 * 2) * 2;
    const size_t hT_bytes     = (size_t)B_ALL * HD * 4 * 2;

    // merged (single-pass) layout needs:
    const size_t xg_m = (size_t)ROWS_ALL * 1024 * 2;   // 256 MB
    const size_t h1_m = (size_t)ROWS_ALL * 256 * 2;    // 64 MB
    const size_t need_m = xg_m + h1_m + hT_bytes + wsplit_bytes;

    char* ws = (char*)d_ws;
    bool merged = (ws_size >= need_m);

    size_t xg_b = merged ? xg_m : (size_t)ROWS * 1024 * 2;
    size_t h1_b = merged ? h1_m : (size_t)ROWS * 256 * 2;

    size_t off = 0;
    unsigned short* xg = (unsigned short*)(ws + off); off += xg_b;
    unsigned short* h1 = (unsigned short*)(ws + off); off += h1_b;
    float* hTf = (float*)(ws + off); off += (size_t)B_ALL * HD * 4;
    float* hTb = (float*)(ws + off); off += (size_t)B_ALL * HD * 4;
    unsigned short* W0hi = (unsigned short*)(ws + off); off += 1024 * 64 * 2;
    unsigned short* W0lo = (unsigned short*)(ws + off); off += 1024 * 64 * 2;
    unsigned short* W1hi = (unsigned short*)(ws + off); off += 1024 * 256 * 2;
    unsigned short* W1lo = (unsigned short*)(ws + off); off += 1024 * 256 * 2;

    split_w<<<(1024 * 64 + 255) / 256, 256, 0, stream>>>(Wih0, W0hi, W0lo, 1024 * 64);
    split_w<<<(1024 * 256 + 255) / 256, 256, 0, stream>>>(Wih1, W1hi, W1lo, 1024 * 256);

    if (merged) {
        // Full 256-batch per dispatch: 512 rec blocks -> 2 blocks/CU -> 4 waves/SIMD.
        // Independent recurrences co-resident on each CU fill each other's
        // latency stalls (rec was 13% occupancy, 65% stall at 1 block/CU).
        gates_gemm_mfma<3, float><<<dim3(ROWS_ALL / 128, 8), 256, 0, stream>>>(
            X, W0hi, W0lo, b0, len, xg, D_INP);
        lstm_rec<<<2 * B_ALL, 512, 0, stream>>>(xg, Whh0, len, h1,
                                                nullptr, nullptr, 0, 8);
        gates_gemm_mfma<2, unsigned short><<<dim3(ROWS_ALL / 128, 8), 256, 0, stream>>>(
            h1, W1hi, W1lo, b1, len, xg, 2 * HD);
        lstm_rec<<<2 * B_ALL, 512, 0, stream>>>(xg, Whh1, len, nullptr,
                                                hTf, hTb, 0, 8);
    } else {
        for (int ch = 0; ch < 2; ++ch) {
            const int* lc = len + ch * BCH;
            const float* Xc = X + (size_t)ch * BCH * T_LEN * D_INP;

            gates_gemm_mfma<3, float><<<dim3(ROWS / 128, 8), 256, 0, stream>>>(
                Xc, W0hi, W0lo, b0, lc, xg, D_INP);
            lstm_rec<<<2 * BCH, 512, 0, stream>>>(xg, Whh0, lc, h1,
                                                  nullptr, nullptr, 0, 7);
            gates_gemm_mfma<2, unsigned short><<<dim3(ROWS / 128, 8), 256, 0, stream>>>(
                h1, W1hi, W1lo, b1, lc, xg, 2 * HD);
            lstm_rec<<<2 * BCH, 512, 0, stream>>>(xg, Whh1, lc, nullptr,
                                                  hTf, hTb, ch * BCH, 7);
        }
    }
    fc_lsm<<<1, 256, 0, stream>>>(hTf, hTb, Wfc, bfc, out);
}

// Round 6
// 2364.547 us; speedup vs baseline: 1.1822x; 1.0005x over previous
//
#include <hip/hip_runtime.h>
#include <hip/hip_bf16.h>
#include <cstdint>
#include <cstddef>
#include <type_traits>

#define B_ALL 256
#define T_LEN 512
#define D_INP 64
#define HD    128
#define G4    512            // 4*H
#define NC    12
#define BCH   128            // batch per chunk
#define ROWS  (BCH * T_LEN)  // 65536 rows per chunk

// ---------- helpers ----------
__device__ __forceinline__ float bf2f(unsigned short u) {
    union { unsigned int i; float f; } v; v.i = ((unsigned int)u) << 16; return v.f;
}
__device__ __forceinline__ unsigned short f2bf(float f) {
    union { float f; unsigned int i; } v; v.f = f;
    unsigned int r = v.i + 0x7FFFu + ((v.i >> 16) & 1u);  // round-nearest-even
    return (unsigned short)(r >> 16);
}
__device__ __forceinline__ float sigf(float x) { return 1.0f / (1.0f + __expf(-x)); }
__device__ __forceinline__ float tanh_f(float x) {
    float xx = fminf(15.0f, fmaxf(-15.0f, x));
    float e = __expf(2.0f * xx);
    return (e - 1.0f) / (e + 1.0f);
}

// LDS-only barrier: drains lgkmcnt but leaves global loads/stores in flight.
#define LDS_BARRIER() asm volatile("s_waitcnt lgkmcnt(0)\n\ts_barrier" ::: "memory")

using bf16x8 = __attribute__((ext_vector_type(8))) short;
using f32x4  = __attribute__((ext_vector_type(4))) float;

// XOR swizzle for [R][32] bf16 LDS tiles (64B rows).
__device__ __forceinline__ int swz(int r, int kb) {
    return (r * 64 + kb) ^ ((r & 3) << 4);
}

// ---------- W split: fp32 -> hi/lo bf16 pair (hi+lo ~ fp32 exact) ----------
__global__ __launch_bounds__(256)
void split_w(const float* __restrict__ w, unsigned short* __restrict__ hi,
             unsigned short* __restrict__ lo, int n)
{
    int i = blockIdx.x * 256 + threadIdx.x;
    if (i < n) {
        float f = w[i];
        unsigned short h = f2bf(f);
        hi[i] = h;
        lo[i] = f2bf(f - bf2f(h));
    }
}

// ---------- gates GEMM (MFMA, split-precision bf16) — unchanged from R3 ----------
template <int TERMS, typename TA>
__global__ __launch_bounds__(256)
void gates_gemm_mfma(const TA* __restrict__ A,
                     const unsigned short* __restrict__ Whi_g,
                     const unsigned short* __restrict__ Wlo_g,
                     const float* __restrict__ bias,
                     const int* __restrict__ lens,
                     unsigned short* __restrict__ out, int K)
{
    int row0 = blockIdx.x * 128;
    int col0 = blockIdx.y * 128;
    int bl = row0 >> 9;
    int t0 = row0 & (T_LEN - 1);
    if (t0 >= lens[bl]) return;

    __shared__ __align__(16) char smem[TERMS == 3 ? 32768 : 24576];
    char* sAhi = smem;                 // [128][32] bf16, swizzled
    char* sWhi = smem + 8192;
    char* sWlo = smem + 16384;
    char* sAlo = (TERMS == 3) ? smem + 24576 : smem;

    int tid = threadIdx.x;
    int l   = tid & 63;
    int w   = tid >> 6;
    int wr  = (w >> 1) * 64;
    int wc  = (w & 1) * 64;

    f32x4 acc[4][4];
#pragma unroll
    for (int mi = 0; mi < 4; ++mi)
#pragma unroll
        for (int ni = 0; ni < 4; ++ni) acc[mi][ni] = (f32x4){0.f, 0.f, 0.f, 0.f};

    int fr = l & 15;
    int fk = (l >> 4) * 16;

    for (int kt = 0; kt < K; kt += 32) {
#pragma unroll
        for (int q = 0; q < 2; ++q) {
            int c = tid + 256 * q;
            int r = c >> 2, kc = c & 3;
            size_t gi = (size_t)(col0 + r) * K + kt + kc * 8;
            *(uint4*)(sWhi + swz(r, kc * 16)) = *(const uint4*)&Whi_g[gi];
            *(uint4*)(sWlo + swz(r, kc * 16)) = *(const uint4*)&Wlo_g[gi];
        }
        if constexpr (std::is_same<TA, unsigned short>::value) {
#pragma unroll
            for (int q = 0; q < 2; ++q) {
                int c = tid + 256 * q;
                int r = c >> 2, kc = c & 3;
                *(uint4*)(sAhi + swz(r, kc * 16)) =
                    *(const uint4*)&A[(size_t)(row0 + r) * K + kt + kc * 8];
            }
        } else {
#pragma unroll
            for (int q = 0; q < 4; ++q) {
                int c = tid + 256 * q;
                int r = c >> 3, kc = c & 7;
                float4 f = *(const float4*)&A[(size_t)(row0 + r) * K + kt + kc * 4];
                ushort4 h, lo;
                h.x = f2bf(f.x); lo.x = f2bf(f.x - bf2f(h.x));
                h.y = f2bf(f.y); lo.y = f2bf(f.y - bf2f(h.y));
                h.z = f2bf(f.z); lo.z = f2bf(f.z - bf2f(h.z));
                h.w = f2bf(f.w); lo.w = f2bf(f.w - bf2f(h.w));
                *(ushort4*)(sAhi + swz(r, kc * 8)) = h;
                *(ushort4*)(sAlo + swz(r, kc * 8)) = lo;
            }
        }
        __syncthreads();

        bf16x8 ah[4], al[4], bh[4], bl4[4];
#pragma unroll
        for (int mi = 0; mi < 4; ++mi) {
            int off = swz(wr + mi * 16 + fr, fk);
            ah[mi] = *(const bf16x8*)(sAhi + off);
            if (TERMS == 3) al[mi] = *(const bf16x8*)(sAlo + off);
        }
#pragma unroll
        for (int ni = 0; ni < 4; ++ni) {
            int off = swz(wc + ni * 16 + fr, fk);
            bh[ni]  = *(const bf16x8*)(sWhi + off);
            bl4[ni] = *(const bf16x8*)(sWlo + off);
        }
#pragma unroll
        for (int mi = 0; mi < 4; ++mi)
#pragma unroll
            for (int ni = 0; ni < 4; ++ni) {
                acc[mi][ni] = __builtin_amdgcn_mfma_f32_16x16x32_bf16(
                    ah[mi], bh[ni], acc[mi][ni], 0, 0, 0);
                acc[mi][ni] = __builtin_amdgcn_mfma_f32_16x16x32_bf16(
                    ah[mi], bl4[ni], acc[mi][ni], 0, 0, 0);
                if (TERMS == 3)
                    acc[mi][ni] = __builtin_amdgcn_mfma_f32_16x16x32_bf16(
                        al[mi], bh[ni], acc[mi][ni], 0, 0, 0);
            }
        __syncthreads();
    }

    int r4 = (l >> 4) * 4;
#pragma unroll
    for (int ni = 0; ni < 4; ++ni) {
        int col = col0 + wc + ni * 16 + fr;
        float bj = bias[col];
#pragma unroll
        for (int mi = 0; mi < 4; ++mi) {
            int row = row0 + wr + mi * 16 + r4;
            f32x4 v = acc[mi][ni];
#pragma unroll
            for (int r = 0; r < 4; ++r)
                out[(size_t)(row + r) * 1024 + col] = f2bf(v[r] + bj);
        }
    }
}

// ---------- LSTM recurrence (R6: 1024 threads, 4 waves/SIMD) ----------
// Same proven R2 dataflow, but tid = ks*256 + rr2 with each thread computing
// TWO gate rows (rr2, rr2+256) over its 32-wide k-slice. Total FMA unchanged;
// wave count doubles to 16 (4 waves/SIMD) so the dot phase's LDS/FMA-chain
// latency is hidden 4-deep instead of 2-deep (rec was 13% occupancy, ~65%
// stall at 8 waves). w shrinks to 2x32=64 VGPR -> fits the <=128 VGPR cap a
// 1024-thread block needs. gp layout, 2-wave nonlinearity, barrier structure
// all identical to R2.
__global__ __launch_bounds__(1024)
void lstm_rec(const unsigned short* __restrict__ xg,   // [ROWS][1024]
              const float* __restrict__ Whh,           // [2][512][128]
              const int* __restrict__ lens,            // chunk-offset
              unsigned short* __restrict__ hs,         // [ROWS][256] or null
              float* __restrict__ hTf, float* __restrict__ hTb,
              int bOff)
{
    int dir = blockIdx.x >> 7;   // 128 batch per chunk
    int bl  = blockIdx.x & 127;
    int L   = lens[bl];
    int tid = threadIdx.x;
    int ks  = tid >> 8;          // k-quarter 0..3 (wave-uniform: ks = wave>>2)
    int rr2 = tid & 255;         // first gate row; second is rr2+256

    __shared__ float h_s[HD];
    __shared__ float gp[4][G4];

    // w[g][kk] = Whh[dir][g*256 + rr2][ks*32 + kk], g in {0,1}
    float w[2][32];
#pragma unroll
    for (int g = 0; g < 2; ++g) {
        const float* wrow = Whh + ((size_t)dir * G4 + g * 256 + rr2) * HD + ks * 32;
#pragma unroll
        for (int k = 0; k < 32; k += 4) {
            float4 v = *(const float4*)(wrow + k);
            w[g][k] = v.x; w[g][k + 1] = v.y; w[g][k + 2] = v.z; w[g][k + 3] = v.w;
        }
    }

    if (tid < HD) h_s[tid] = 0.0f;
    float c = 0.0f, hkeep = 0.0f;
    __syncthreads();

    const unsigned short* xgb = xg + (size_t)bl * T_LEN * 1024 + (size_t)dir * G4;
    int tt   = dir ? (L - 1) : 0;
    int step = dir ? -1 : 1;

    float xv0 = 0.f, xv1 = 0.f, xv2 = 0.f, xv3 = 0.f;
    if (tid < HD) {
        const unsigned short* p = xgb + (size_t)tt * 1024;
        xv0 = bf2f(p[tid]);       xv1 = bf2f(p[tid + 128]);
        xv2 = bf2f(p[tid + 256]); xv3 = bf2f(p[tid + 384]);
    }

    for (int t = 0; t < L; ++t) {
        // ---- dot: 2 independent 32-deep chains, 16 waves ----
        float a0 = 0.f, a1 = 0.f;
        const float* hq = &h_s[ks * 32];
#pragma unroll
        for (int k = 0; k < 32; k += 4) {
            float4 h4 = *(const float4*)(hq + k);   // wave-uniform broadcast
            a0 += w[0][k] * h4.x + w[0][k+1] * h4.y + w[0][k+2] * h4.z + w[0][k+3] * h4.w;
            a1 += w[1][k] * h4.x + w[1][k+1] * h4.y + w[1][k+2] * h4.z + w[1][k+3] * h4.w;
        }
        gp[ks][rr2]       = a0;
        gp[ks][rr2 + 256] = a1;
        LDS_BARRIER();

        // ---- reduce + nonlinearity: waves 0-1 (ks==0, rr2<128) ----
        if (tid < HD) {
            float gi = xv0 + ((gp[0][tid]       + gp[1][tid])       + (gp[2][tid]       + gp[3][tid]));
            float gf = xv1 + ((gp[0][tid + 128] + gp[1][tid + 128]) + (gp[2][tid + 128] + gp[3][tid + 128]));
            float gg = xv2 + ((gp[0][tid + 256] + gp[1][tid + 256]) + (gp[2][tid + 256] + gp[3][tid + 256]));
            float go = xv3 + ((gp[0][tid + 384] + gp[1][tid + 384]) + (gp[2][tid + 384] + gp[3][tid + 384]));

            int ttn = (t + 1 < L) ? (tt + step) : tt;
            const unsigned short* p = xgb + (size_t)ttn * 1024;
            xv0 = bf2f(p[tid]);       xv1 = bf2f(p[tid + 128]);
            xv2 = bf2f(p[tid + 256]); xv3 = bf2f(p[tid + 384]);

            float ig = sigf(gi);
            float fg = sigf(gf);
            float G  = tanh_f(gg);
            float og = sigf(go);
            c = fg * c + ig * G;
            float hn = og * tanh_f(c);
            h_s[tid] = hn;
            hkeep = hn;
            if (hs) hs[(size_t)(bl * T_LEN + tt) * 256 + dir * HD + tid] = f2bf(hn);
        }
        LDS_BARRIER();
        tt += step;
    }
    if (hTf && tid < HD) {
        (dir ? hTb : hTf)[(size_t)(bOff + bl) * HD + tid] = hkeep;
    }
}

// ---------- final FC + log_softmax ----------
__global__ __launch_bounds__(256)
void fc_lsm(const float* __restrict__ hTf, const float* __restrict__ hTb,
            const float* __restrict__ Wfc, const float* __restrict__ bfc,
            float* __restrict__ out)
{
    int b = threadIdx.x;
    const float* hb = hTb + (size_t)b * HD;
    const float* hf = hTf + (size_t)b * HD;
    float l[NC];
#pragma unroll
    for (int cc = 0; cc < NC; ++cc) {
        const float* wr = Wfc + cc * 256;
        float acc = bfc[cc];
        for (int k = 0; k < HD; k += 4) {
            acc += hb[k] * wr[k] + hb[k + 1] * wr[k + 1]
                 + hb[k + 2] * wr[k + 2] + hb[k + 3] * wr[k + 3];
            acc += hf[k] * wr[128 + k] + hf[k + 1] * wr[128 + k + 1]
                 + hf[k + 2] * wr[128 + k + 2] + hf[k + 3] * wr[128 + k + 3];
        }
        l[cc] = acc;
    }
    float m = l[0];
#pragma unroll
    for (int cc = 1; cc < NC; ++cc) m = fmaxf(m, l[cc]);
    float s = 0.0f;
#pragma unroll
    for (int cc = 0; cc < NC; ++cc) s += __expf(l[cc] - m);
    float lg = m + logf(s);
#pragma unroll
    for (int cc = 0; cc < NC; ++cc) out[(size_t)b * NC + cc] = l[cc] - lg;
}

extern "C" void kernel_launch(void* const* d_in, const int* in_sizes, int n_in,
                              void* d_out, int out_size, void* d_ws, size_t ws_size,
                              hipStream_t stream)
{
    const float* X    = (const float*)d_in[0];
    const int*   len  = (const int*)d_in[1];
    const float* Wih0 = (const float*)d_in[2];   // (2,512,64)  -> (1024,64)
    const float* Whh0 = (const float*)d_in[3];   // (2,512,128)
    const float* b0   = (const float*)d_in[4];   // (2,512) -> (1024)
    const float* Wih1 = (const float*)d_in[5];   // (2,512,256) -> (1024,256)
    const float* Whh1 = (const float*)d_in[6];
    const float* b1   = (const float*)d_in[7];
    const float* Wfc  = (const float*)d_in[8];   // (12,256)
    const float* bfc  = (const float*)d_in[9];   // (12)
    float* out = (float*)d_out;

    char* ws = (char*)d_ws;
    size_t off = 0;
    unsigned short* xg = (unsigned short*)(ws + off); off += (size_t)ROWS * 1024 * 2;
    unsigned short* h1 = (unsigned short*)(ws + off); off += (size_t)ROWS * 256 * 2;
    float* hTf = (float*)(ws + off); off += (size_t)B_ALL * HD * 4;
    float* hTb = (float*)(ws + off); off += (size_t)B_ALL * HD * 4;
    unsigned short* W0hi = (unsigned short*)(ws + off); off += 1024 * 64 * 2;
    unsigned short* W0lo = (unsigned short*)(ws + off); off += 1024 * 64 * 2;
    unsigned short* W1hi = (unsigned short*)(ws + off); off += 1024 * 256 * 2;
    unsigned short* W1lo = (unsigned short*)(ws + off); off += 1024 * 256 * 2;

    split_w<<<(1024 * 64 + 255) / 256, 256, 0, stream>>>(Wih0, W0hi, W0lo, 1024 * 64);
    split_w<<<(1024 * 256 + 255) / 256, 256, 0, stream>>>(Wih1, W1hi, W1lo, 1024 * 256);

    for (int ch = 0; ch < 2; ++ch) {
        const int* lc = len + ch * BCH;
        const float* Xc = X + (size_t)ch * BCH * T_LEN * D_INP;

        gates_gemm_mfma<3, float><<<dim3(ROWS / 128, 8), 256, 0, stream>>>(
            Xc, W0hi, W0lo, b0, lc, xg, D_INP);
        lstm_rec<<<2 * BCH, 1024, 0, stream>>>(xg, Whh0, lc, h1,
                                               nullptr, nullptr, 0);
        gates_gemm_mfma<2, unsigned short><<<dim3(ROWS / 128, 8), 256, 0, stream>>>(
            h1, W1hi, W1lo, b1, lc, xg, 2 * HD);
        lstm_rec<<<2 * BCH, 1024, 0, stream>>>(xg, Whh1, lc, nullptr,
                                               hTf, hTb, ch * BCH);
    }
    fc_lsm<<<1, 256, 0, stream>>>(hTf, hTb, Wfc, bfc, out);
}